// Round 1
// baseline (134.209 us; speedup 1.0000x reference)
//
#include <hip/hip_runtime.h>

// Problem constants (from reference): B=16, T=256, SD=24, AD=8, K=32, H=1, HD1=HD2=256
#define NB 16
#define NT 256
#define NK 32
#define NROWS (NB * NT)          // 4096
static constexpr float INV_SQRT_K = 0.17677669529663687f;  // 1/sqrt(32)

// ---------------------------------------------------------------------------
// Kernel 1: s = concat(state, action); q = relu(Wq s + bq); Ks = Wk s; Vs = Wv s
// Also writes s into xcat[..., 32:64] so the MLP kernel reads one buffer.
// Linearity trick: kk[b,i,j] = relu(Ks[b,j] - Ks[b,i] + bk) — bias added later.
// ---------------------------------------------------------------------------
__global__ __launch_bounds__(256) void prep_kernel(
    const float* __restrict__ state, const float* __restrict__ action,
    const float* __restrict__ Wq, const float* __restrict__ bq,
    const float* __restrict__ Wk, const float* __restrict__ Wv,
    float* __restrict__ q, float* __restrict__ Ks, float* __restrict__ Vs,
    float* __restrict__ xcat)
{
    __shared__ float s_sh[8][32];
    const int tid = threadIdx.x;
    const int r = tid >> 5, n = tid & 31;
    const int row = blockIdx.x * 8 + r;
    float sval = (n < 24) ? state[row * 24 + n] : action[row * 8 + (n - 24)];
    s_sh[r][n] = sval;
    __syncthreads();
    float aq = 0.f, ak = 0.f, av = 0.f;
#pragma unroll
    for (int k = 0; k < 32; ++k) {
        float sv = s_sh[r][k];
        aq = fmaf(sv, Wq[n * 32 + k], aq);
        ak = fmaf(sv, Wk[n * 32 + k], ak);
        av = fmaf(sv, Wv[n * 32 + k], av);
    }
    q[row * 32 + n]  = fmaxf(aq + bq[n], 0.f);
    Ks[row * 32 + n] = ak;
    Vs[row * 32 + n] = av;
    xcat[row * 64 + 32 + n] = sval;   // s part of the MLP input concat
}

// ---------------------------------------------------------------------------
// Kernel 2: attention. One block per (b, i). 256 threads.
// Phase 1: thread j computes score_j = sum_k relu(Ks[b,j,k]-Ks[b,i,k]+bk)*q[b,i,k]
// Softmax over j (block reduce). Phase 2: (k, j-group) threads accumulate
// x[k] = sum_j w_j * relu(Vs[b,j,k]-Vs[b,i,k]+bv).  Writes xcat[..., 0:32].
// ---------------------------------------------------------------------------
__global__ __launch_bounds__(256) void attn_kernel(
    const float* __restrict__ q, const float* __restrict__ Ks,
    const float* __restrict__ Vs, const float* __restrict__ bk,
    const float* __restrict__ bv, float* __restrict__ xcat)
{
    __shared__ float Ki[32], Vi[32], qi[32], bks[32], bvs[32];
    __shared__ float sc[256];
    __shared__ float wred[4];
    __shared__ float part[8][32];
    const int tid = threadIdx.x;
    const int b = blockIdx.x >> 8, i = blockIdx.x & 255;
    const int ibase = (b * 256 + i) * 32;
    if (tid < 32) {
        Ki[tid]  = Ks[ibase + tid];
        Vi[tid]  = Vs[ibase + tid];
        qi[tid]  = q[ibase + tid];
        bks[tid] = bk[tid];
        bvs[tid] = bv[tid];
    }
    __syncthreads();

    // ---- phase 1: scores (thread = column j) ----
    const int j = tid;
    const float* kp = Ks + (b * 256 + j) * 32;
    float acc = 0.f;
#pragma unroll
    for (int k = 0; k < 32; ++k) {
        float kkv = fmaxf(kp[k] - Ki[k] + bks[k], 0.f);
        acc = fmaf(kkv, qi[k], acc);
    }
    const float sval = acc * INV_SQRT_K;

    // ---- softmax over j: block max ----
    float m = sval;
#pragma unroll
    for (int off = 32; off >= 1; off >>= 1) m = fmaxf(m, __shfl_xor(m, off));
    if ((tid & 63) == 0) wred[tid >> 6] = m;
    __syncthreads();
    m = fmaxf(fmaxf(wred[0], wred[1]), fmaxf(wred[2], wred[3]));
    const float e = expf(sval - m);
    float ssum = e;
#pragma unroll
    for (int off = 32; off >= 1; off >>= 1) ssum += __shfl_xor(ssum, off);
    __syncthreads();               // everyone done reading wred(max)
    if ((tid & 63) == 0) wred[tid >> 6] = ssum;
    __syncthreads();
    const float tot = (wred[0] + wred[1]) + (wred[2] + wred[3]);
    sc[j] = e / tot;               // softmax weight w_j
    __syncthreads();

    // ---- phase 2: x[k] = sum_j w_j * relu(Vs[b,j,k] - Vi[k] + bv[k]) ----
    const int k = tid & 31, g = tid >> 5;         // 8 j-groups of 32
    const float* vp = Vs + (b * 256 + g * 32) * 32;
    const float vi = Vi[k], bvk = bvs[k];
    float xacc = 0.f;
#pragma unroll
    for (int jj = 0; jj < 32; ++jj) {
        float vv = fmaxf(vp[jj * 32 + k] - vi + bvk, 0.f);
        xacc = fmaf(sc[g * 32 + jj], vv, xacc);
    }
    part[g][k] = xacc;
    __syncthreads();
    if (tid < 32) {
        float x = 0.f;
#pragma unroll
        for (int gg = 0; gg < 8; ++gg) x += part[gg][tid];
        xcat[(b * 256 + i) * 64 + tid] = x;       // attention part of concat
    }
}

// ---------------------------------------------------------------------------
// Kernel 3: MLP.  8 rows per block, thread-per-output-neuron with 8-row
// weight reuse (each W1/W2 element loaded once per block, used 8x).
// h1 = relu(W1 xcat + b1); h2 = relu(W2 h1 + b2); out = Wout h2 + bout.
// ---------------------------------------------------------------------------
__global__ __launch_bounds__(256) void mlp_kernel(
    const float* __restrict__ xcat,
    const float* __restrict__ W1, const float* __restrict__ b1,
    const float* __restrict__ W2, const float* __restrict__ b2,
    const float* __restrict__ Wout, const float* __restrict__ bout,
    float* __restrict__ out)
{
    __shared__ float xc[8][64];
    __shared__ float h1[8][256];
    __shared__ float h2[8][256];
    const int tid = threadIdx.x;
    const int row0 = blockIdx.x * 8;

    ((float*)xc)[tid]       = xcat[row0 * 64 + tid];
    ((float*)xc)[tid + 256] = xcat[row0 * 64 + tid + 256];
    __syncthreads();

    const int m = tid;                    // output neuron
    float acc[8];
#pragma unroll
    for (int r = 0; r < 8; ++r) acc[r] = 0.f;
    const float* w1p = W1 + m * 64;
#pragma unroll 8
    for (int n = 0; n < 64; ++n) {
        float w = w1p[n];
#pragma unroll
        for (int r = 0; r < 8; ++r) acc[r] = fmaf(w, xc[r][n], acc[r]);
    }
    float bb = b1[m];
#pragma unroll
    for (int r = 0; r < 8; ++r) h1[r][m] = fmaxf(acc[r] + bb, 0.f);
    __syncthreads();

#pragma unroll
    for (int r = 0; r < 8; ++r) acc[r] = 0.f;
    const float* w2p = W2 + m * 256;
#pragma unroll 4
    for (int n = 0; n < 256; ++n) {
        float w = w2p[n];
#pragma unroll
        for (int r = 0; r < 8; ++r) acc[r] = fmaf(w, h1[r][n], acc[r]);
    }
    bb = b2[m];
#pragma unroll
    for (int r = 0; r < 8; ++r) h2[r][m] = fmaxf(acc[r] + bb, 0.f);
    __syncthreads();

    // out row: 16 lanes per row, strided partials, 16-lane shuffle reduce
    if (tid < 128) {
        const int r = tid >> 4, l = tid & 15;
        float a = 0.f;
        for (int n = l; n < 256; n += 16) a = fmaf(h2[r][n], Wout[n], a);
#pragma unroll
        for (int mm = 8; mm >= 1; mm >>= 1) a += __shfl_xor(a, mm);
        if (l == 0) out[row0 + r] = a + bout[0];
    }
}

// ---------------------------------------------------------------------------
extern "C" void kernel_launch(void* const* d_in, const int* in_sizes, int n_in,
                              void* d_out, int out_size, void* d_ws, size_t ws_size,
                              hipStream_t stream)
{
    const float* state  = (const float*)d_in[0];
    const float* action = (const float*)d_in[1];
    const float* Wq     = (const float*)d_in[2];
    const float* bq     = (const float*)d_in[3];
    const float* Wk     = (const float*)d_in[4];
    const float* bk     = (const float*)d_in[5];
    const float* Wv     = (const float*)d_in[6];
    const float* bv     = (const float*)d_in[7];
    const float* W1     = (const float*)d_in[8];
    const float* b1     = (const float*)d_in[9];
    const float* W2     = (const float*)d_in[10];
    const float* b2     = (const float*)d_in[11];
    const float* Wout   = (const float*)d_in[12];
    const float* bout   = (const float*)d_in[13];
    float* out = (float*)d_out;

    float* ws   = (float*)d_ws;
    float* q    = ws;                     // 4096*32
    float* Ks   = q  + NROWS * NK;        // 4096*32
    float* Vs   = Ks + NROWS * NK;        // 4096*32
    float* xcat = Vs + NROWS * NK;        // 4096*64

    prep_kernel<<<NROWS / 8, 256, 0, stream>>>(state, action, Wq, bq, Wk, Wv,
                                               q, Ks, Vs, xcat);
    attn_kernel<<<NROWS, 256, 0, stream>>>(q, Ks, Vs, bk, bv, xcat);
    mlp_kernel<<<NROWS / 8, 256, 0, stream>>>(xcat, W1, b1, W2, b2, Wout, bout, out);
}

// Round 3
// 122.555 us; speedup vs baseline: 1.0951x; 1.0951x over previous
//
#include <hip/hip_runtime.h>

// Problem constants: B=16, T=256, SD=24, AD=8, K=32, H=1, HD1=HD2=256
#define NB 16
#define NT 256
#define NK 32
#define NROWS (NB * NT)          // 4096
#define GQ 4                     // query rows per attention block
static constexpr float INV_SQRT_K = 0.17677669529663687f;  // 1/sqrt(32)

// ---------------------------------------------------------------------------
// Kernel 1: s = concat(state, action);
//   q   = relu(Wq s + bq) * 1/sqrt(K)      (scale folded in)
//   Ksb = Wk s + bk                        (bias folded:   kk = relu(Ksb[j]-Kieff))
//   Vsb = Wv s + bv
// Also writes s into xcat[..., 32:64] for the MLP concat.
// ---------------------------------------------------------------------------
__global__ __launch_bounds__(256) void prep_kernel(
    const float* __restrict__ state, const float* __restrict__ action,
    const float* __restrict__ Wq, const float* __restrict__ bq,
    const float* __restrict__ Wk, const float* __restrict__ bk,
    const float* __restrict__ Wv, const float* __restrict__ bv,
    float* __restrict__ q, float* __restrict__ Ksb, float* __restrict__ Vsb,
    float* __restrict__ xcat)
{
    __shared__ float s_sh[8][32];
    const int tid = threadIdx.x;
    const int r = tid >> 5, n = tid & 31;
    const int row = blockIdx.x * 8 + r;
    float sval = (n < 24) ? state[row * 24 + n] : action[row * 8 + (n - 24)];
    s_sh[r][n] = sval;
    __syncthreads();
    float aq = 0.f, ak = 0.f, av = 0.f;
#pragma unroll
    for (int k = 0; k < 32; ++k) {
        float sv = s_sh[r][k];
        aq = fmaf(sv, Wq[n * 32 + k], aq);
        ak = fmaf(sv, Wk[n * 32 + k], ak);
        av = fmaf(sv, Wv[n * 32 + k], av);
    }
    q[row * 32 + n]   = fmaxf(aq + bq[n], 0.f) * INV_SQRT_K;
    Ksb[row * 32 + n] = ak + bk[n];
    Vsb[row * 32 + n] = av + bv[n];
    xcat[row * 64 + 32 + n] = sval;   // s part of the MLP input concat
}

// ---------------------------------------------------------------------------
// Kernel 2: attention, GQ=4 query rows per block (1024 blocks x 256 threads).
// Phase 1: thread j holds Ksb row j in 32 VGPRs, computes scores for all 4 i's.
// Softmax: wave g reduces row g (wave-local shuffles, no extra barriers).
// Phase 2: each Vsb element loaded once, reused for the 4 i's.
// ---------------------------------------------------------------------------
__global__ __launch_bounds__(256) void attn_kernel(
    const float* __restrict__ q, const float* __restrict__ Ksb,
    const float* __restrict__ Vsb, const float* __restrict__ bk,
    const float* __restrict__ bv, float* __restrict__ xcat)
{
    __shared__ float Kie[GQ][32];   // Ksb[i_g] - bk  (so kk = relu(krow - Kie))
    __shared__ float Vie[GQ][32];   // Vsb[i_g] - bv  (so vv = relu(vrow - Vie))
    __shared__ float qi[GQ][32];    // pre-scaled q rows
    __shared__ float sc[GQ][256];
    __shared__ float part[GQ][8][32];
    const int tid = threadIdx.x;
    const int b  = blockIdx.x >> 6;           // 64 blocks per batch
    const int i0 = (blockIdx.x & 63) << 2;    // first of 4 query rows
    const int rowbase = b * 256;

    {
        const int g = (tid >> 5) & 3, k = tid & 31;
        const int ib = (rowbase + i0 + g) * 32 + k;
        if (tid < 128) {
            Kie[g][k] = Ksb[ib] - bk[k];
            qi[g][k]  = q[ib];
        } else {
            Vie[g][k] = Vsb[ib] - bv[k];
        }
    }
    __syncthreads();

    // ---- phase 1: scores (thread = column j, all 4 i's) ----
    const int j = tid;
    const float4* kp4 = (const float4*)(Ksb + (rowbase + j) * 32);
    float kr[32];
#pragma unroll
    for (int u = 0; u < 8; ++u) {
        float4 v = kp4[u];
        kr[u * 4 + 0] = v.x; kr[u * 4 + 1] = v.y;
        kr[u * 4 + 2] = v.z; kr[u * 4 + 3] = v.w;
    }
    float acc[GQ] = {0.f, 0.f, 0.f, 0.f};
#pragma unroll
    for (int k = 0; k < 32; ++k) {
        float kv = kr[k];
#pragma unroll
        for (int g = 0; g < GQ; ++g)
            acc[g] = fmaf(fmaxf(kv - Kie[g][k], 0.f), qi[g][k], acc[g]);
    }
#pragma unroll
    for (int g = 0; g < GQ; ++g) sc[g][j] = acc[g];
    __syncthreads();

    // ---- softmax: wave w owns row g=w (64 lanes x 4 elements) ----
    {
        const int g = tid >> 6, l = tid & 63;
        float e0 = sc[g][l], e1 = sc[g][l + 64], e2 = sc[g][l + 128], e3 = sc[g][l + 192];
        float m = fmaxf(fmaxf(e0, e1), fmaxf(e2, e3));
#pragma unroll
        for (int off = 32; off >= 1; off >>= 1) m = fmaxf(m, __shfl_xor(m, off));
        e0 = expf(e0 - m); e1 = expf(e1 - m); e2 = expf(e2 - m); e3 = expf(e3 - m);
        float ssum = ((e0 + e1) + (e2 + e3));
#pragma unroll
        for (int off = 32; off >= 1; off >>= 1) ssum += __shfl_xor(ssum, off);
        float inv = 1.f / ssum;
        sc[g][l] = e0 * inv; sc[g][l + 64] = e1 * inv;
        sc[g][l + 128] = e2 * inv; sc[g][l + 192] = e3 * inv;
    }
    __syncthreads();

    // ---- phase 2: x_g[k] = sum_j w_g[j] * relu(Vsb[j][k] - Vie[g][k]) ----
    {
        const int k = tid & 31, grp = tid >> 5;   // 8 j-groups of 32
        const float* vp = Vsb + (rowbase + grp * 32) * 32;
        float vie[GQ];
#pragma unroll
        for (int g = 0; g < GQ; ++g) vie[g] = Vie[g][k];
        float xacc[GQ] = {0.f, 0.f, 0.f, 0.f};
#pragma unroll
        for (int jj = 0; jj < 32; ++jj) {
            float v = vp[jj * 32 + k];
#pragma unroll
            for (int g = 0; g < GQ; ++g)
                xacc[g] = fmaf(sc[g][grp * 32 + jj], fmaxf(v - vie[g], 0.f), xacc[g]);
        }
#pragma unroll
        for (int g = 0; g < GQ; ++g) part[g][grp][k] = xacc[g];
    }
    __syncthreads();
    if (tid < 128) {
        const int g = tid >> 5, k = tid & 31;
        float x = 0.f;
#pragma unroll
        for (int gg = 0; gg < 8; ++gg) x += part[g][gg][k];
        xcat[(rowbase + i0 + g) * 64 + k] = x;
    }
}

// ---------------------------------------------------------------------------
// Kernel 3: MLP. 8 rows/block, thread-per-neuron, 8-row weight reuse.
// ---------------------------------------------------------------------------
__global__ __launch_bounds__(256) void mlp_kernel(
    const float* __restrict__ xcat,
    const float* __restrict__ W1, const float* __restrict__ b1,
    const float* __restrict__ W2, const float* __restrict__ b2,
    const float* __restrict__ Wout, const float* __restrict__ bout,
    float* __restrict__ out)
{
    __shared__ float xc[8][64];
    __shared__ float h1[8][256];
    __shared__ float h2[8][256];
    const int tid = threadIdx.x;
    const int row0 = blockIdx.x * 8;

    ((float*)xc)[tid]       = xcat[row0 * 64 + tid];
    ((float*)xc)[tid + 256] = xcat[row0 * 64 + tid + 256];
    __syncthreads();

    const int m = tid;
    float acc[8];
#pragma unroll
    for (int r = 0; r < 8; ++r) acc[r] = 0.f;
    const float* w1p = W1 + m * 64;
#pragma unroll 8
    for (int n = 0; n < 64; ++n) {
        float w = w1p[n];
#pragma unroll
        for (int r = 0; r < 8; ++r) acc[r] = fmaf(w, xc[r][n], acc[r]);
    }
    float bb = b1[m];
#pragma unroll
    for (int r = 0; r < 8; ++r) h1[r][m] = fmaxf(acc[r] + bb, 0.f);
    __syncthreads();

#pragma unroll
    for (int r = 0; r < 8; ++r) acc[r] = 0.f;
    const float* w2p = W2 + m * 256;
#pragma unroll 4
    for (int n = 0; n < 256; ++n) {
        float w = w2p[n];
#pragma unroll
        for (int r = 0; r < 8; ++r) acc[r] = fmaf(w, h1[r][n], acc[r]);
    }
    bb = b2[m];
#pragma unroll
    for (int r = 0; r < 8; ++r) h2[r][m] = fmaxf(acc[r] + bb, 0.f);
    __syncthreads();

    if (tid < 128) {
        const int r = tid >> 4, l = tid & 15;
        float a = 0.f;
        for (int n = l; n < 256; n += 16) a = fmaf(h2[r][n], Wout[n], a);
#pragma unroll
        for (int mm = 8; mm >= 1; mm >>= 1) a += __shfl_xor(a, mm);
        if (l == 0) out[row0 + r] = a + bout[0];
    }
}

// ---------------------------------------------------------------------------
extern "C" void kernel_launch(void* const* d_in, const int* in_sizes, int n_in,
                              void* d_out, int out_size, void* d_ws, size_t ws_size,
                              hipStream_t stream)
{
    const float* state  = (const float*)d_in[0];
    const float* action = (const float*)d_in[1];
    const float* Wq     = (const float*)d_in[2];
    const float* bq     = (const float*)d_in[3];
    const float* Wk     = (const float*)d_in[4];
    const float* bk     = (const float*)d_in[5];
    const float* Wv     = (const float*)d_in[6];
    const float* bv     = (const float*)d_in[7];
    const float* W1     = (const float*)d_in[8];
    const float* b1     = (const float*)d_in[9];
    const float* W2     = (const float*)d_in[10];
    const float* b2     = (const float*)d_in[11];
    const float* Wout   = (const float*)d_in[12];
    const float* bout   = (const float*)d_in[13];
    float* out = (float*)d_out;

    float* ws   = (float*)d_ws;
    float* q    = ws;                     // 4096*32
    float* Ksb  = q   + NROWS * NK;       // 4096*32
    float* Vsb  = Ksb + NROWS * NK;       // 4096*32
    float* xcat = Vsb + NROWS * NK;       // 4096*64

    prep_kernel<<<NROWS / 8, 256, 0, stream>>>(state, action, Wq, bq, Wk, bk,
                                               Wv, bv, q, Ksb, Vsb, xcat);
    attn_kernel<<<NROWS / GQ, 256, 0, stream>>>(q, Ksb, Vsb, bk, bv, xcat);
    mlp_kernel<<<NROWS / 8, 256, 0, stream>>>(xcat, W1, b1, W2, b2, Wout, bout, out);
}

// Round 4
// 116.455 us; speedup vs baseline: 1.1524x; 1.0524x over previous
//
#include <hip/hip_runtime.h>

typedef float f32x4 __attribute__((ext_vector_type(4)));

// Problem constants: B=16, T=256, SD=24, AD=8, K=32, H=1, HD1=HD2=256
#define NB 16
#define NT 256
#define NK 32
#define NROWS (NB * NT)          // 4096
#define GQ 8                     // query rows per fused block (= MLP row group)
static constexpr float INV_SQRT_K = 0.17677669529663687f;  // 1/sqrt(32)

// ---------------------------------------------------------------------------
// Kernel 1: s = concat(state, action);
//   q   = relu(Wq s + bq) * 1/sqrt(K)   (scale folded)
//   Ksb = Wk s + bk                     (bias folded: kk = relu(Ksb[j]-Kie))
//   Vsb = Wv s + bv
//   sbuf = s  (for the MLP concat)
// ---------------------------------------------------------------------------
__global__ __launch_bounds__(256) void prep_kernel(
    const float* __restrict__ state, const float* __restrict__ action,
    const float* __restrict__ Wq, const float* __restrict__ bq,
    const float* __restrict__ Wk, const float* __restrict__ bk,
    const float* __restrict__ Wv, const float* __restrict__ bv,
    float* __restrict__ q, float* __restrict__ Ksb, float* __restrict__ Vsb,
    float* __restrict__ sbuf)
{
    __shared__ float s_sh[8][32];
    const int tid = threadIdx.x;
    const int r = tid >> 5, n = tid & 31;
    const int row = blockIdx.x * 8 + r;
    float sval = (n < 24) ? state[row * 24 + n] : action[row * 8 + (n - 24)];
    s_sh[r][n] = sval;
    __syncthreads();
    float aq = 0.f, ak = 0.f, av = 0.f;
#pragma unroll
    for (int k = 0; k < 32; ++k) {
        float sv = s_sh[r][k];
        aq = fmaf(sv, Wq[n * 32 + k], aq);
        ak = fmaf(sv, Wk[n * 32 + k], ak);
        av = fmaf(sv, Wv[n * 32 + k], av);
    }
    q[row * 32 + n]    = fmaxf(aq + bq[n], 0.f) * INV_SQRT_K;
    Ksb[row * 32 + n]  = ak + bk[n];
    Vsb[row * 32 + n]  = av + bv[n];
    sbuf[row * 32 + n] = sval;
}

// ---------------------------------------------------------------------------
// Kernel 2: fused attention + MLP.  512 blocks x 256 threads; block handles
// 8 query rows of one batch.  All broadcast LDS reads are f32x4 (b128).
// ---------------------------------------------------------------------------
__global__ __launch_bounds__(256) void fused_kernel(
    const float* __restrict__ q, const float* __restrict__ Ksb,
    const float* __restrict__ Vsb, const float* __restrict__ bk,
    const float* __restrict__ bv, const float* __restrict__ sbuf,
    const float* __restrict__ W1, const float* __restrict__ b1,
    const float* __restrict__ W2, const float* __restrict__ b2,
    const float* __restrict__ Wout, const float* __restrict__ bout,
    float* __restrict__ out)
{
    __shared__ float Kie[GQ][32];    // Ksb[i_g] - bk  (kk = relu(krow - Kie))
    __shared__ float Vie[GQ][32];    // Vsb[i_g] - bv  (vv = relu(vrow - Vie))
    __shared__ float qis[GQ][32];    // pre-scaled q rows
    __shared__ float sc[GQ][256];    // scores -> softmax weights
    __shared__ float part[GQ][8][32];
    __shared__ float xc[GQ][64];     // MLP input concat
    __shared__ float h1[GQ][256];
    __shared__ float h2[GQ][256];

    const int tid = threadIdx.x;
    const int b  = blockIdx.x >> 5;          // 32 blocks per batch
    const int i0 = (blockIdx.x & 31) << 3;   // first of 8 query rows
    const int rowbase = b * 256;
    const int grow0 = rowbase + i0;

    {   // stage the 8 i-rows: 256 threads = 8 g x 32 k
        const int g = tid >> 5, k = tid & 31;
        const int ib = (grow0 + g) * 32 + k;
        Kie[g][k] = Ksb[ib] - bk[k];
        qis[g][k] = q[ib];
        Vie[g][k] = Vsb[ib] - bv[k];
    }
    __syncthreads();

    // ---- phase 1: scores (thread = column j, 8 i's) ----
    {
        const int j = tid;
        const f32x4* kp4 = (const f32x4*)(Ksb + (rowbase + j) * 32);
        f32x4 kr[8];
#pragma unroll
        for (int u = 0; u < 8; ++u) kr[u] = kp4[u];
        float acc[GQ] = {};
#pragma unroll
        for (int k4 = 0; k4 < 8; ++k4) {
            f32x4 kv = kr[k4];
#pragma unroll
            for (int g = 0; g < GQ; ++g) {
                f32x4 ki = ((const f32x4*)Kie[g])[k4];
                f32x4 qv = ((const f32x4*)qis[g])[k4];
                acc[g] = fmaf(fmaxf(kv[0] - ki[0], 0.f), qv[0], acc[g]);
                acc[g] = fmaf(fmaxf(kv[1] - ki[1], 0.f), qv[1], acc[g]);
                acc[g] = fmaf(fmaxf(kv[2] - ki[2], 0.f), qv[2], acc[g]);
                acc[g] = fmaf(fmaxf(kv[3] - ki[3], 0.f), qv[3], acc[g]);
            }
        }
#pragma unroll
        for (int g = 0; g < GQ; ++g) sc[g][j] = acc[g];
    }
    __syncthreads();

    // ---- softmax: wave w handles rows w and w+4 (wave-local shuffles) ----
    {
        const int w = tid >> 6, l = tid & 63;
#pragma unroll
        for (int rr = 0; rr < 2; ++rr) {
            const int g = w + rr * 4;
            float e0 = sc[g][l],       e1 = sc[g][l + 64];
            float e2 = sc[g][l + 128], e3 = sc[g][l + 192];
            float m = fmaxf(fmaxf(e0, e1), fmaxf(e2, e3));
#pragma unroll
            for (int off = 32; off >= 1; off >>= 1) m = fmaxf(m, __shfl_xor(m, off));
            e0 = expf(e0 - m); e1 = expf(e1 - m);
            e2 = expf(e2 - m); e3 = expf(e3 - m);
            float ssum = (e0 + e1) + (e2 + e3);
#pragma unroll
            for (int off = 32; off >= 1; off >>= 1) ssum += __shfl_xor(ssum, off);
            float inv = 1.f / ssum;
            sc[g][l] = e0 * inv;       sc[g][l + 64] = e1 * inv;
            sc[g][l + 128] = e2 * inv; sc[g][l + 192] = e3 * inv;
        }
    }
    __syncthreads();

    // ---- phase 2: x_g[k] = sum_j w_g[j] * relu(Vsb[j][k] - Vie[g][k]) ----
    {
        const int k = tid & 31, grp = tid >> 5;   // 8 j-groups of 32
        const float* vp = Vsb + (rowbase + grp * 32) * 32 + k;
        float vie[GQ];
#pragma unroll
        for (int g = 0; g < GQ; ++g) vie[g] = Vie[g][k];
        float xacc[GQ] = {};
#pragma unroll
        for (int jc = 0; jc < 8; ++jc) {          // 4 j's per chunk
            f32x4 w4[GQ];
#pragma unroll
            for (int g = 0; g < GQ; ++g) w4[g] = ((const f32x4*)&sc[g][grp * 32])[jc];
#pragma unroll
            for (int u = 0; u < 4; ++u) {
                float v = vp[(jc * 4 + u) * 32];
#pragma unroll
                for (int g = 0; g < GQ; ++g)
                    xacc[g] = fmaf(w4[g][u], fmaxf(v - vie[g], 0.f), xacc[g]);
            }
        }
#pragma unroll
        for (int g = 0; g < GQ; ++g) part[g][grp][k] = xacc[g];
    }
    __syncthreads();

    // ---- assemble MLP input: xc = [attn_x | s] ----
    {
        const int g = tid >> 5, k = tid & 31;
        float x = 0.f;
#pragma unroll
        for (int gg = 0; gg < 8; ++gg) x += part[g][gg][k];
        xc[g][k] = x;
        xc[g][32 + k] = sbuf[(grow0 + g) * 32 + k];
    }
    __syncthreads();

    // ---- MLP layer 1: thread = neuron m, 8-row reuse ----
    const int m = tid;
    {
        f32x4 wreg[16];
        const f32x4* w1p4 = (const f32x4*)(W1 + m * 64);
#pragma unroll
        for (int u = 0; u < 16; ++u) wreg[u] = w1p4[u];
        float acc[GQ] = {};
#pragma unroll
        for (int n4 = 0; n4 < 16; ++n4) {
            f32x4 w = wreg[n4];
#pragma unroll
            for (int r = 0; r < GQ; ++r) {
                f32x4 x = ((const f32x4*)xc[r])[n4];
                acc[r] = fmaf(w[0], x[0], fmaf(w[1], x[1],
                         fmaf(w[2], x[2], fmaf(w[3], x[3], acc[r]))));
            }
        }
        float bb = b1[m];
#pragma unroll
        for (int r = 0; r < GQ; ++r) h1[r][m] = fmaxf(acc[r] + bb, 0.f);
    }
    __syncthreads();

    // ---- MLP layer 2 ----
    {
        const f32x4* w2p4 = (const f32x4*)(W2 + m * 256);
        float acc[GQ] = {};
#pragma unroll 8
        for (int n4 = 0; n4 < 64; ++n4) {
            f32x4 w = w2p4[n4];
#pragma unroll
            for (int r = 0; r < GQ; ++r) {
                f32x4 h = ((const f32x4*)h1[r])[n4];
                acc[r] = fmaf(w[0], h[0], fmaf(w[1], h[1],
                         fmaf(w[2], h[2], fmaf(w[3], h[3], acc[r]))));
            }
        }
        float bb = b2[m];
#pragma unroll
        for (int r = 0; r < GQ; ++r) h2[r][m] = fmaxf(acc[r] + bb, 0.f);
    }
    __syncthreads();

    // ---- output row: 16 lanes per row, f32x4 partials, shuffle reduce ----
    if (tid < 128) {
        const int r = tid >> 4, l = tid & 15;
        const f32x4* wo4 = (const f32x4*)Wout;
        float a = 0.f;
#pragma unroll
        for (int n4 = l; n4 < 64; n4 += 16) {
            f32x4 w = wo4[n4];
            f32x4 h = ((const f32x4*)h2[r])[n4];
            a = fmaf(w[0], h[0], fmaf(w[1], h[1],
                fmaf(w[2], h[2], fmaf(w[3], h[3], a))));
        }
#pragma unroll
        for (int mm = 8; mm >= 1; mm >>= 1) a += __shfl_xor(a, mm);
        if (l == 0) out[grow0 + r] = a + bout[0];
    }
}

// ---------------------------------------------------------------------------
extern "C" void kernel_launch(void* const* d_in, const int* in_sizes, int n_in,
                              void* d_out, int out_size, void* d_ws, size_t ws_size,
                              hipStream_t stream)
{
    const float* state  = (const float*)d_in[0];
    const float* action = (const float*)d_in[1];
    const float* Wq     = (const float*)d_in[2];
    const float* bq     = (const float*)d_in[3];
    const float* Wk     = (const float*)d_in[4];
    const float* bk     = (const float*)d_in[5];
    const float* Wv     = (const float*)d_in[6];
    const float* bv     = (const float*)d_in[7];
    const float* W1     = (const float*)d_in[8];
    const float* b1     = (const float*)d_in[9];
    const float* W2     = (const float*)d_in[10];
    const float* b2     = (const float*)d_in[11];
    const float* Wout   = (const float*)d_in[12];
    const float* bout   = (const float*)d_in[13];
    float* out = (float*)d_out;

    float* ws   = (float*)d_ws;
    float* q    = ws;                     // 4096*32
    float* Ksb  = q    + NROWS * NK;      // 4096*32
    float* Vsb  = Ksb  + NROWS * NK;      // 4096*32
    float* sbuf = Vsb  + NROWS * NK;      // 4096*32

    prep_kernel<<<NROWS / 8, 256, 0, stream>>>(state, action, Wq, bq, Wk, bk,
                                               Wv, bv, q, Ksb, Vsb, sbuf);
    fused_kernel<<<NROWS / GQ, 256, 0, stream>>>(q, Ksb, Vsb, bk, bv, sbuf,
                                                 W1, b1, W2, b2, Wout, bout, out);
}